// Round 11
// baseline (78.105 us; speedup 1.0000x reference)
//
#include <hip/hip_runtime.h>
#include <cstdint>
#include <cstddef>

#define BATCH 32
#define IMH 512
#define IMW 512
#define KMAX 256
#define NB 4096          // histogram bins: key bits [63:52] = sign|exp|3-mantissa

// K1: register rolling-window NMS. Wave = 256 cols (4/lane), RPW output rows.
#define RPW 8
#define NBLKX 2
#define NBLKY 16
#define NBLK (NBLKX * NBLKY)   // 32 blocks/image
#define LCAP 2048              // 256x32 tile, ~910 expected candidates; 2.2x headroom

#define TPB2 1024              // tail kernel threads (16 waves for latency hiding)
#define SKEYS 6144             // tail LDS cap for in-bin* keys

typedef unsigned long long u64;
typedef unsigned short u16;

__device__ __forceinline__ float sigmoidf_(float x) {
    return 1.0f / (1.0f + expf(-x));
}
__device__ __forceinline__ float scoref_(float r, float u) {
    const float sg = sigmoidf_(r);
    return sg * sg * (1.0f - 0.35f * sigmoidf_(u));
}

// ---------------------------------------------------------------------------
// K1: fused score + 3x3 NMS (register rolling window) + per-block candidate
// segment + per-block 4096-bin histogram (plain u16 stores). No global
// atomics, no pre-zeroed state.
// key = (score_bits<<32) | ~idx -> unsigned desc == (score desc, idx asc),
// matching lax.top_k's stable tie-break.
// ---------------------------------------------------------------------------
__global__ __launch_bounds__(256)
void score_nms_kernel(const float* __restrict__ route,
                      const float* __restrict__ unc,
                      u64* __restrict__ cand,
                      int* __restrict__ blkcnt,
                      u16* __restrict__ blkhist) {
    const int b    = blockIdx.z;
    const int tid  = threadIdx.x;
    const int w    = tid >> 6;
    const int lane = tid & 63;
    const int y0   = (blockIdx.y * 4 + w) * RPW;
    const int x0   = blockIdx.x * 256 + lane * 4;
    const int blk  = blockIdx.y * NBLKX + blockIdx.x;

    __shared__ u64 lcand[LCAP];          // 16 KB
    __shared__ unsigned hist[NB];        // 16 KB
    __shared__ int lcnt;
    if (tid == 0) lcnt = 0;
    for (int i = tid; i < NB; i += 256) hist[i] = 0;
    __syncthreads();

    const float* rB = route + (size_t)b * IMH * IMW;
    const float* uB = unc   + (size_t)b * IMH * IMW;

    int ex = -1;
    if (lane == 0)       ex = x0 - 1;
    else if (lane == 63) ex = x0 + 4;
    const bool eAct = (ex >= 0 && ex < IMW);

    const u64 laneMaskLt = (1ull << lane) - 1ull;

    float sP[4], hP1[4], hP2[4];
    #pragma unroll
    for (int j = 0; j < 4; ++j) { sP[j] = -INFINITY; hP1[j] = -INFINITY; hP2[j] = -INFINITY; }

    const int ylast = y0 + RPW;
    bool v = (y0 - 1 >= 0);
    float4 r4, u4; float er = 0.f, eu = 0.f;
    if (v) {
        r4 = *(const float4*)(rB + (size_t)(y0 - 1) * IMW + x0);
        u4 = *(const float4*)(uB + (size_t)(y0 - 1) * IMW + x0);
        if (eAct) { er = rB[(size_t)(y0 - 1) * IMW + ex]; eu = uB[(size_t)(y0 - 1) * IMW + ex]; }
    }

    for (int y = y0 - 1; y <= ylast; ++y) {
        const int yn = y + 1;
        const bool vn = (yn <= ylast) && (yn < IMH);
        float4 r4n, u4n; float ern = 0.f, eun = 0.f;
        if (vn) {
            r4n = *(const float4*)(rB + (size_t)yn * IMW + x0);
            u4n = *(const float4*)(uB + (size_t)yn * IMW + x0);
            if (eAct) { ern = rB[(size_t)yn * IMW + ex]; eun = uB[(size_t)yn * IMW + ex]; }
        }

        float sC[4], hmC[4];
        float es = -INFINITY;
        if (v && eAct) es = scoref_(er, eu);
        if (v) {
            sC[0] = scoref_(r4.x, u4.x);
            sC[1] = scoref_(r4.y, u4.y);
            sC[2] = scoref_(r4.z, u4.z);
            sC[3] = scoref_(r4.w, u4.w);
        } else {
            sC[0] = sC[1] = sC[2] = sC[3] = -INFINITY;
        }
        float lft = __shfl_up(sC[3], 1, 64);
        if (lane == 0) lft = es;
        float rgt = __shfl_down(sC[0], 1, 64);
        if (lane == 63) rgt = es;
        if (v) {
            hmC[0] = fmaxf(fmaxf(lft,   sC[0]), sC[1]);
            hmC[1] = fmaxf(fmaxf(sC[0], sC[1]), sC[2]);
            hmC[2] = fmaxf(fmaxf(sC[1], sC[2]), sC[3]);
            hmC[3] = fmaxf(fmaxf(sC[2], sC[3]), rgt);
        } else {
            hmC[0] = hmC[1] = hmC[2] = hmC[3] = -INFINITY;
        }

        if (y >= y0 + 1) {
            const int yo = y - 1;
            bool p[4]; int cntT = 0;
            #pragma unroll
            for (int j = 0; j < 4; ++j) {
                const float m9 = fmaxf(fmaxf(hP2[j], hP1[j]), hmC[j]);
                p[j] = (sP[j] >= m9);
                cntT += p[j] ? 1 : 0;
            }
            const u64 B0 = __ballot(cntT & 1);
            const u64 B1 = __ballot(cntT & 2);
            const u64 B2 = __ballot(cntT & 4);
            const int total = __popcll(B0) + 2 * __popcll(B1) + 4 * __popcll(B2);
            if (total > 0) {
                const int prefix = __popcll(B0 & laneMaskLt) + 2 * __popcll(B1 & laneMaskLt)
                                 + 4 * __popcll(B2 & laneMaskLt);
                int wbase = 0;
                if (lane == 0) wbase = atomicAdd(&lcnt, total);
                wbase = __shfl(wbase, 0, 64);
                int mb = wbase + prefix;
                #pragma unroll
                for (int j = 0; j < 4; ++j) {
                    if (p[j]) {
                        const unsigned idx = (unsigned)(yo * IMW + (x0 + j));
                        const u64 key = ((u64)__float_as_uint(sP[j]) << 32) | (unsigned)(~idx);
                        if (mb < LCAP) lcand[mb] = key;
                        ++mb;
                    }
                }
            }
        }

        #pragma unroll
        for (int j = 0; j < 4; ++j) { hP2[j] = hP1[j]; hP1[j] = hmC[j]; sP[j] = sC[j]; }
        r4 = r4n; u4 = u4n; er = ern; eu = eun; v = vn;
    }

    __syncthreads();
    const int m = (lcnt < LCAP) ? lcnt : LCAP;

    for (int i = tid; i < m; i += 256)
        atomicAdd(&hist[(unsigned)(lcand[i] >> 52)], 1u);

    u64* seg = cand + ((size_t)b * NBLK + blk) * LCAP;
    for (int i = tid; i < m; i += 256) seg[i] = lcand[i];
    if (tid == 0) blkcnt[b * NBLK + blk] = m;
    __syncthreads();

    unsigned* hout = (unsigned*)(blkhist + ((size_t)b * NBLK + blk) * NB);
    for (int i = tid; i < NB / 2; i += 256)
        hout[i] = (hist[2 * i] & 0xFFFFu) | (hist[2 * i + 1] << 16);
}

// ---------------------------------------------------------------------------
// K2 (tail): 1 block/image x 1024 threads (16 waves: latency hiding).
//   merge 32 block-hists -> tot[4096] (static loops, u64 loads)
//   1024-chunk suffix-scan -> exact threshold bin bstar
//   ONE static-bound split scan of candidates (ballot-aggregated LDS appends)
//   13-nibble radix-select -> exact threshold key T; collect; bitonic; epilogue
// ---------------------------------------------------------------------------
__global__ __launch_bounds__(TPB2)
void tail_kernel(const u64* __restrict__ cand,
                 const int* __restrict__ blkcnt,
                 const u16* __restrict__ blkhist,
                 const float* __restrict__ scale,
                 const float* __restrict__ unc,
                 const int* __restrict__ imh,
                 const int* __restrict__ imw,
                 float* __restrict__ rois,
                 float* __restrict__ scoresOut,
                 float* __restrict__ validOut) {
    const int b    = blockIdx.x;
    const int tid  = threadIdx.x;
    const int lane = tid & 63;

    __shared__ unsigned tot[NB];           // 16 KB
    __shared__ u64 skeys[SKEYS];           // 48 KB
    __shared__ u64 sel[KMAX];              // 2 KB
    __shared__ unsigned sA[TPB2];          // 4 KB
    __shared__ unsigned csS[TPB2];         // 4 KB
    __shared__ int segc[NBLK];
    __shared__ unsigned h2[16];
    __shared__ u64 prefS;
    __shared__ int bstarS, rem2S, cSel, cSk;

    if (tid < NBLK) segc[tid] = blkcnt[b * NBLK + tid];
    if (tid < KMAX) sel[tid] = 0ull;
    if (tid == 0) { bstarS = 0; cSel = 0; cSk = 0; }

    // ---- merge 32 block-hists: thread owns bins 4t..4t+3 (u64 = 4 x u16) ----
    const u64* hb = (const u64*)(blkhist + (size_t)b * NBLK * NB);
    unsigned s0 = 0, s1 = 0, s2 = 0, s3 = 0;
    #pragma unroll
    for (int blk = 0; blk < NBLK; ++blk) {
        const u64 q = hb[blk * (NB / 4) + tid];
        s0 += (unsigned)(q & 0xFFFFu);
        s1 += (unsigned)((q >> 16) & 0xFFFFu);
        s2 += (unsigned)((q >> 32) & 0xFFFFu);
        s3 += (unsigned)(q >> 48);
    }
    tot[4 * tid]     = s0;
    tot[4 * tid + 1] = s1;
    tot[4 * tid + 2] = s2;
    tot[4 * tid + 3] = s3;
    const unsigned cs = s0 + s1 + s2 + s3;
    csS[tid] = cs;
    sA[tid]  = cs;
    __syncthreads();

    // ---- inclusive suffix sum over 1024 chunks ----
    for (int off = 1; off < TPB2; off <<= 1) {
        const unsigned vv = sA[tid] + ((tid + off < TPB2) ? sA[tid + off] : 0u);
        __syncthreads();
        sA[tid] = vv;
        __syncthreads();
    }
    const unsigned total = sA[0];
    if (total > (unsigned)KMAX) {
        const unsigned incl = sA[tid];
        const unsigned excl = incl - csS[tid];
        if (excl < (unsigned)KMAX && incl >= (unsigned)KMAX) {
            unsigned acc = excl;
            int bbin = 4 * tid + 3;
            for (; bbin > 4 * tid; --bbin) {
                const unsigned h = tot[bbin];
                if (acc + h >= (unsigned)KMAX) break;
                acc += h;
            }
            bstarS = bbin;
        }
    }
    __syncthreads();
    const unsigned bstar = (unsigned)bstarS;

    // ---- split scan: static 64-iteration flat loop over all segments ----
    const u64* cb = cand + (size_t)b * NBLK * LCAP;
    #pragma unroll 4
    for (int f = tid; f < NBLK * LCAP; f += TPB2) {
        const int blk = f >> 11;           // LCAP = 2048
        const int i   = f & (LCAP - 1);
        const bool vld = (i < segc[blk]);
        u64 k = 0;
        if (vld) k = cb[f];
        const unsigned bin = (unsigned)(k >> 52);
        const bool pS = vld && (bin > bstar);
        const bool pK = vld && (bin == bstar);

        const u64 mS = __ballot(pS);
        if (mS) {
            const int leader = __ffsll(mS) - 1;
            const int wcount = __popcll(mS);
            const int prefix = __popcll(mS & ((1ull << lane) - 1));
            int wb_ = 0;
            if (lane == leader) wb_ = atomicAdd(&cSel, wcount);
            wb_ = __shfl(wb_, leader, 64);
            if (pS) {
                const int pos = wb_ + prefix;
                if (pos < KMAX) sel[pos] = k;
            }
        }
        const u64 mK = __ballot(pK);
        if (mK) {
            const int leader = __ffsll(mK) - 1;
            const int wcount = __popcll(mK);
            const int prefix = __popcll(mK & ((1ull << lane) - 1));
            int wb_ = 0;
            if (lane == leader) wb_ = atomicAdd(&cSk, wcount);
            wb_ = __shfl(wb_, leader, 64);
            if (pK) {
                const int pos = wb_ + prefix;
                if (pos < SKEYS) skeys[pos] = k;
            }
        }
    }
    __syncthreads();
    const int above = cSel;
    int nk = cSk;
    if (nk > SKEYS) nk = SKEYS;
    const int remk = KMAX - above;

    // ---- 13-nibble radix-select (prefix = bstar known) ----
    u64 T = 0;
    if (nk > remk) {
        if (tid == 0) { prefS = (u64)bstar; rem2S = remk; }
        __syncthreads();
        for (int p = 12; p >= 0; --p) {
            if (tid < 16) h2[tid] = 0;
            __syncthreads();
            const u64 pre = prefS;
            for (int i = tid; i < nk; i += TPB2) {
                const u64 k = skeys[i];
                if ((k >> ((p + 1) * 4)) == pre)
                    atomicAdd(&h2[(unsigned)(k >> (p * 4)) & 15u], 1u);
            }
            __syncthreads();
            if (tid == 0) {
                int rem = rem2S;
                int vv;
                for (vv = 15; vv >= 0; --vv) {
                    const int hv = (int)h2[vv];
                    if (rem <= hv) break;
                    rem -= hv;
                }
                if (vv < 0) vv = 0;
                prefS = (pre << 4) | (unsigned)vv;
                rem2S = rem;
            }
            __syncthreads();
        }
        T = prefS;
    }

    // ---- collect in-bin keys >= T (exactly remk when nk > remk) ----
    for (int i0 = 0; i0 < SKEYS; i0 += TPB2) {
        const int i = i0 + tid;
        const bool vld = (i < nk);
        u64 k = 0;
        if (vld) k = skeys[i];
        const bool pC = vld && (k >= T);
        const u64 mC = __ballot(pC);
        if (mC) {
            const int leader = __ffsll(mC) - 1;
            const int wcount = __popcll(mC);
            const int prefix = __popcll(mC & ((1ull << lane) - 1));
            int wb_ = 0;
            if (lane == leader) wb_ = atomicAdd(&cSel, wcount);
            wb_ = __shfl(wb_, leader, 64);
            if (pC) {
                const int pos = wb_ + prefix;
                if (pos < KMAX) sel[pos] = k;
            }
        }
    }
    __syncthreads();

    // ---- bitonic sort descending over sel[256] (keys unique; zeros sink) ----
    for (int kk = 2; kk <= KMAX; kk <<= 1) {
        for (int j = kk >> 1; j > 0; j >>= 1) {
            if (tid < KMAX) {
                const int ixj = tid ^ j;
                if (ixj > tid) {
                    const u64 a  = sel[tid];
                    const u64 bb = sel[ixj];
                    const bool desc = ((tid & kk) == 0);
                    if (desc ? (a < bb) : (a > bb)) {
                        sel[tid] = bb;
                        sel[ixj] = a;
                    }
                }
            }
            __syncthreads();
        }
    }

    // ---- epilogue ----
    if (tid < KMAX) {
        const u64 k = sel[tid];
        const float value = __uint_as_float((unsigned)(k >> 32));
        const bool valid  = (k != 0ull) && (value > 0.0f);

        float r0 = 0.f, r1 = 0.f, r2 = 0.f, r3 = 0.f, r4 = 0.f, sv = 0.f, vv = 0.f;
        if (valid) {
            const unsigned idx = ~(unsigned)(k & 0xFFFFFFFFull);
            const int y = (int)(idx / IMW);
            const int x = (int)(idx % IMW);
            const float cx = ((float)x + 0.5f) * 4.0f;
            const float cy = ((float)y + 0.5f) * 4.0f;
            const float sg = scale[(size_t)b * IMH * IMW + idx];
            const float uu = unc[(size_t)b * IMH * IMW + idx];
            const float su = sigmoidf_(uu);
            float side = 32.0f + sigmoidf_(sg) * (512.0f - 32.0f);
            side = side * (1.0f + 0.25f * su);
            const float half = side * 0.5f;
            const float fw = (float)imw[0];
            const float fh = (float)imh[0];
            r0 = (float)b;
            r1 = fminf(fmaxf(cx - half, 0.0f), fw - 1.0f);
            r2 = fminf(fmaxf(cy - half, 0.0f), fh - 1.0f);
            r3 = fminf(fmaxf(cx + half, 1.0f), fw);
            r4 = fminf(fmaxf(cy + half, 1.0f), fh);
            sv = value;
            vv = 1.0f;
        }
        float* roiP = rois + ((size_t)b * KMAX + tid) * 5;
        roiP[0] = r0; roiP[1] = r1; roiP[2] = r2; roiP[3] = r3; roiP[4] = r4;
        scoresOut[b * KMAX + tid] = sv;
        validOut[b * KMAX + tid]  = vv;
    }
}

extern "C" void kernel_launch(void* const* d_in, const int* in_sizes, int n_in,
                              void* d_out, int out_size, void* d_ws, size_t ws_size,
                              hipStream_t stream) {
    const float* route = (const float*)d_in[0];
    const float* scale = (const float*)d_in[1];
    const float* unc   = (const float*)d_in[2];
    const int*   imh   = (const int*)d_in[3];
    const int*   imw   = (const int*)d_in[4];

    // ws layout (~25 MB): [cand 16.78MB][blkcnt 4KB][blkhist u16 8MB]
    char* ws = (char*)d_ws;
    u64* cand    = (u64*)ws;
    size_t off   = (size_t)BATCH * NBLK * LCAP * sizeof(u64);
    int* blkcnt  = (int*)(ws + off);   off += (size_t)BATCH * NBLK * sizeof(int);
    u16* blkhist = (u16*)(ws + off);

    float* rois      = (float*)d_out;                       // [B, 256, 5]
    float* scoresOut = rois + (size_t)BATCH * KMAX * 5;     // [B, 256]
    float* validOut  = scoresOut + (size_t)BATCH * KMAX;    // [B, 256]

    dim3 grid1(NBLKX, NBLKY, BATCH);
    score_nms_kernel<<<grid1, 256, 0, stream>>>(route, unc, cand, blkcnt, blkhist);

    tail_kernel<<<BATCH, TPB2, 0, stream>>>(cand, blkcnt, blkhist, scale, unc,
                                            imh, imw, rois, scoresOut, validOut);
}